// Round 7
// baseline (11194.080 us; speedup 1.0000x reference)
//
#include <hip/hip_runtime.h>
#include <math.h>

// Problem constants
#define B 128
#define T 1024
#define E 256
#define H 512

// ws layout (floats):
//   h_buf : 2 * [512][128]  (double-buffered, [unit][batch])
//   last_h: [512][128]
//   last_c: [512][128]
//   flags : 8 groups x 64 ints (one 128B slot-line per group; slots 0..31 used)
#define HBUF_OFF   0
#define LASTH_OFF  (2*65536)
#define LASTC_OFF  (3*65536)
#define FLAG_OFF   (4*65536)

// Accurate transcendentals (OCML expf/tanhf).
__device__ __forceinline__ float sigm_f(float x) {
    return 1.f / (1.f + expf(-x));
}
__device__ __forceinline__ float tanh_f(float x) {
    return tanhf(x);
}

// 64-lane reduce-scatter of 32 per-lane values: after this, every lane's v[0]
// holds the full 64-lane sum of value index vi=(lane>>1)&31. All indices are
// compile-time (full unroll) -> stays in registers (no scratch).
__device__ __forceinline__ void reduce32(float (&v)[32], int lane) {
#define RR(MASK, HALF)                                                 \
    {                                                                  \
        const bool hi = (lane & MASK) != 0;                            \
        _Pragma("unroll")                                              \
        for (int i = 0; i < HALF; ++i) {                               \
            const float mine   = hi ? v[i + HALF] : v[i];              \
            const float theirs = hi ? v[i] : v[i + HALF];              \
            v[i] = mine + __shfl_xor(theirs, MASK);                    \
        }                                                              \
    }
    RR(32, 16)
    RR(16, 8)
    RR(8, 4)
    RR(4, 2)
    RR(2, 1)
#undef RR
    v[0] = v[0] + __shfl_xor(v[0], 1);
}

// ---------------------------------------------------------------------------
// Persistent LSTM, whole T=1024 loop in one cooperative kernel.
// R6 -> R7: 256 blocks x **512 threads** (8 waves), __launch_bounds__(512,2)
// => register budget 512/2 = 256 VGPR/wave. Each wave owns TWO units
// (96 VGPR of weights) held genuinely register-resident across all steps.
// Rationale: three rounds proved the allocator caps 1024-thread blocks at
// 64 VGPR, forcing per-step weight reloads (R4) or AGPR shuttling (R5/R6).
// Per-SIMD arithmetic is unchanged (2 waves x 2x work); the reload tax goes.
//
// g = bid>>5 (8 batch groups of 16 rows), m = bid&31 (32 unit groups of 16).
// Wave w in [0,8) owns units m*16 + 2w and m*16 + 2w + 1.
//
// Per-step schedule (unchanged from R4 except loop widths):
//   A: x-part dots batches 0..7, both units (no h dep, hides exchange)
//   B: wait h(t) flags (wave 0 polls LLC; LDS s_go release)
//   C: stage h(t) -> LDS; sync
//   D: h-part batches 0..7 both units; reduce32 x2; sgate
//   E: full dots batches 8..15 both units; reduce32 x2; sgate
//   F: x(t+1) prefetch to regs; sync (sgate ready);
//      epilogue (tid<256) + h sc-stores; all threads write x(t+1) to LDS;
//      drain-sync; tid0 flag(t+1) store
// Race-freedom: flag=k means "I finished reading h(k-1) AND my h(k) is at
// the LLC". Writers of h(t+2) run only after seeing all flags>=t+1, i.e.
// after every peer finished reading h(t) -> buffer (t&1) safe to overwrite.
// Protocol unchanged since R4 (proven).
__global__ __launch_bounds__(512, 2) void lstm_persistent(
    const int* __restrict__ tokens, const float* __restrict__ emb,
    const float* __restrict__ W_ih, const float* __restrict__ b_ih,
    const float* __restrict__ W_hh, const float* __restrict__ b_hh,
    const float* __restrict__ h0, const float* __restrict__ c0,
    float* __restrict__ ws) {
    const int tid = threadIdx.x, bid = blockIdx.x;
    const int g = bid >> 5, m = bid & 31;

    float* h_buf  = ws + HBUF_OFF;
    float* last_h = ws + LASTH_OFF;
    float* last_c = ws + LASTC_OFF;
    int*   flags  = (int*)(ws + FLAG_OFF) + g * 64;   // 32 slots in one line

    __shared__ __align__(16) float xh[16 * 772];   // [b][k], row stride 772
    __shared__ float sgate[4][16][17];             // [gate][unit-local][batch]
    __shared__ int   s_L[16];                      // per-batch Lsteps
    __shared__ float s_c[256];                     // c[ul*16+b], block-owned
    __shared__ int   s_go;                         // intra-block release flag
    __shared__ float lds_pad[8192];                // 32KB pad -> LDS>80KB -> 1 block/CU

    // volatile touch: not removable by DCE (keeps the occupancy limiter)
    {
        volatile float* vp = lds_pad;
        for (int i = tid; i < 8192; i += 512) vp[i] = 0.f;
    }
    if (tid == 0) s_go = 0;

    // ---- per-batch lengths (all 32 blocks of a group compute identical s_L/Tg)
    if (tid < 16) s_L[tid] = T;
    __syncthreads();
    {
        const int b = tid >> 5;                     // 16 rows x 32 threads
        const int* tb = tokens + (size_t)(g * 16 + b) * T;
        int fz = T;
        for (int p = (tid & 31); p < T; p += 32)
            if (tb[p] == 0) fz = min(fz, p);
        atomicMin(&s_L[b], fz);
    }
    __syncthreads();
    if (tid < 16) {
        const int f = s_L[tid];
        s_L[tid] = (f == 0 || f == T) ? T : f;
    }
    __syncthreads();
    int Tg = 0;
#pragma unroll
    for (int i = 0; i < 16; ++i) Tg = max(Tg, s_L[i]);

    // ---- init block-owned c tile
    if (tid < 256) {
        const int uli = tid >> 4, bi = tid & 15;
        s_c[tid] = c0[(size_t)(g * 16 + bi) * H + (m * 16 + uli)];
    }

    // ---- stage x(0): 16 rows x 64 f4 = 1024 f4, 2 per thread
    {
        const int b = tid >> 5, j = tid & 31;
        const int tok = tokens[(size_t)(g * 16 + b) * T + 0];
        const float4* er = ((const float4*)emb) + (size_t)tok * 64;
        float4* dst = (float4*)&xh[b * 772];
        dst[j]      = er[j];
        dst[32 + j] = er[32 + j];
    }

    // ---- wave/lane roles + REGISTER-PERSISTENT weights (2 units/wave)
    const int lane = tid & 63;
    const int w    = tid >> 6;            // wave index in [0,8)
    const int uA   = m * 16 + 2 * w;      // first owned unit
    const int uB   = uA + 1;              // second owned unit
    const float4* Wi4 = (const float4*)W_ih;
    const float4* Wh4 = (const float4*)W_hh;
    float4 wxA[4], whA0[4], whA1[4];      // 12 f4 = 48 VGPR (unit A)
    float4 wxB[4], whB0[4], whB1[4];      // 12 f4 = 48 VGPR (unit B)
#pragma unroll
    for (int G = 0; G < 4; ++G) {
        wxA[G]  = Wi4[((size_t)G * H + uA) * 64 + lane];
        whA0[G] = Wh4[((size_t)G * H + uA) * 128 + lane];
        whA1[G] = Wh4[((size_t)G * H + uA) * 128 + 64 + lane];
        wxB[G]  = Wi4[((size_t)G * H + uB) * 64 + lane];
        whB0[G] = Wh4[((size_t)G * H + uB) * 128 + lane];
        whB1[G] = Wh4[((size_t)G * H + uB) * 128 + 64 + lane];
    }

    // ---- epilogue constants (used for tid<256; loads in-bounds for all)
    const int ul2 = tid >> 4, b2 = tid & 15;
    const int unit2 = m * 16 + (ul2 & 15);
    const int bg = g * 16 + b2;
    const float bi_i = b_ih[unit2],         bh_i = b_hh[unit2];
    const float bi_f = b_ih[H + unit2],     bh_f = b_hh[H + unit2];
    const float bi_g = b_ih[2 * H + unit2], bh_g = b_hh[2 * H + unit2];
    const float bi_o = b_ih[3 * H + unit2], bh_o = b_hh[3 * H + unit2];

    __syncthreads();   // x(0), s_L, s_c, s_go visible

    float vA[32], vB[32];

    for (int t = 0; t < Tg; ++t) {
        // ---- Phase A: x-part, batches 0..7, both units (hides exchange)
#pragma unroll
        for (int bb = 0; bb < 8; ++bb) {
            const float4 x = ((const float4*)&xh[bb * 772])[lane];
#pragma unroll
            for (int G = 0; G < 4; ++G) {
                float p = wxA[G].x * x.x;
                p = fmaf(wxA[G].y, x.y, p);
                p = fmaf(wxA[G].z, x.z, p);
                p = fmaf(wxA[G].w, x.w, p);
                vA[G * 8 + bb] = p;
                float q = wxB[G].x * x.x;
                q = fmaf(wxB[G].y, x.y, q);
                q = fmaf(wxB[G].z, x.z, q);
                q = fmaf(wxB[G].w, x.w, q);
                vB[G * 8 + bb] = q;
            }
        }

        // ---- Phase B: wait for h(t) (wave 0 polls LLC; LDS release)
        if (t > 0) {
            if (tid < 64) {
                const int* slot = &flags[tid & 31];
                while (true) {
                    const int fv = __hip_atomic_load(slot, __ATOMIC_RELAXED,
                                                     __HIP_MEMORY_SCOPE_AGENT);
                    if (__all(fv >= t)) break;
                    __builtin_amdgcn_s_sleep(1);
                }
                if (tid == 0)
                    __hip_atomic_store(&s_go, t, __ATOMIC_RELAXED,
                                       __HIP_MEMORY_SCOPE_WORKGROUP);
            } else {
                while (__hip_atomic_load(&s_go, __ATOMIC_RELAXED,
                                         __HIP_MEMORY_SCOPE_WORKGROUP) < t)
                    __builtin_amdgcn_s_sleep(1);
            }
        }

        // ---- Phase C: stage h(t) into xh[b][256+u]
        if (t == 0) {
            // from h0 (b-major): 16 rows x 128 f4 = 2048 f4, 4 per thread
            const int b = tid >> 5, l = tid & 31;
            const float4* h04 = (const float4*)(h0 + (size_t)(g * 16 + b) * H);
            float4* dst = (float4*)&xh[b * 772 + 256];
            dst[l]      = h04[l];
            dst[32 + l] = h04[32 + l];
            dst[64 + l] = h04[64 + l];
            dst[96 + l] = h04[96 + l];
        } else {
            // coherent 8B loads from LLC (bypass L1/L2; no cache maintenance)
            const unsigned long long* hs8 = (const unsigned long long*)
                (h_buf + (size_t)(t & 1) * (H * B));
            float2 hv[8];
#pragma unroll
            for (int j = 0; j < 8; ++j) {
                const int idx = j * 512 + tid;         // [0,4096)
                const int u = idx >> 3, bp = idx & 7;
                unsigned long long val = __hip_atomic_load(
                    &hs8[(size_t)u * 64 + g * 8 + bp],
                    __ATOMIC_RELAXED, __HIP_MEMORY_SCOPE_AGENT);
                hv[j] = __builtin_bit_cast(float2, val);
            }
#pragma unroll
            for (int j = 0; j < 8; ++j) {
                const int idx = j * 512 + tid;
                const int u = idx >> 3, bp = idx & 7;
                xh[(2 * bp) * 772 + 256 + u]     = hv[j].x;
                xh[(2 * bp + 1) * 772 + 256 + u] = hv[j].y;
            }
        }
        __syncthreads();   // sync 1/3

        // ---- Phase D: h-part batches 0..7, both units; reduce; sgate
#pragma unroll
        for (int bb = 0; bb < 8; ++bb) {
            const float4 ha = ((const float4*)&xh[bb * 772])[64 + lane];
            const float4 hb = ((const float4*)&xh[bb * 772])[128 + lane];
#pragma unroll
            for (int G = 0; G < 4; ++G) {
                float p = vA[G * 8 + bb];
                p = fmaf(whA0[G].x, ha.x, p);
                p = fmaf(whA0[G].y, ha.y, p);
                p = fmaf(whA0[G].z, ha.z, p);
                p = fmaf(whA0[G].w, ha.w, p);
                p = fmaf(whA1[G].x, hb.x, p);
                p = fmaf(whA1[G].y, hb.y, p);
                p = fmaf(whA1[G].z, hb.z, p);
                p = fmaf(whA1[G].w, hb.w, p);
                vA[G * 8 + bb] = p;
                float q = vB[G * 8 + bb];
                q = fmaf(whB0[G].x, ha.x, q);
                q = fmaf(whB0[G].y, ha.y, q);
                q = fmaf(whB0[G].z, ha.z, q);
                q = fmaf(whB0[G].w, ha.w, q);
                q = fmaf(whB1[G].x, hb.x, q);
                q = fmaf(whB1[G].y, hb.y, q);
                q = fmaf(whB1[G].z, hb.z, q);
                q = fmaf(whB1[G].w, hb.w, q);
                vB[G * 8 + bb] = q;
            }
        }
        reduce32(vA, lane);
        if ((lane & 1) == 0) {
            const int vi = (lane >> 1) & 31;
            sgate[vi >> 3][2 * w][vi & 7] = vA[0];
        }
        reduce32(vB, lane);
        if ((lane & 1) == 0) {
            const int vi = (lane >> 1) & 31;
            sgate[vi >> 3][2 * w + 1][vi & 7] = vB[0];
        }

        // ---- Phase E: full dots batches 8..15, both units; reduce; sgate
#pragma unroll
        for (int bb = 0; bb < 8; ++bb) {
            const float4 x  = ((const float4*)&xh[(8 + bb) * 772])[lane];
            const float4 ha = ((const float4*)&xh[(8 + bb) * 772])[64 + lane];
            const float4 hb = ((const float4*)&xh[(8 + bb) * 772])[128 + lane];
#pragma unroll
            for (int G = 0; G < 4; ++G) {
                float p = wxA[G].x * x.x;
                p = fmaf(wxA[G].y, x.y, p);
                p = fmaf(wxA[G].z, x.z, p);
                p = fmaf(wxA[G].w, x.w, p);
                p = fmaf(whA0[G].x, ha.x, p);
                p = fmaf(whA0[G].y, ha.y, p);
                p = fmaf(whA0[G].z, ha.z, p);
                p = fmaf(whA0[G].w, ha.w, p);
                p = fmaf(whA1[G].x, hb.x, p);
                p = fmaf(whA1[G].y, hb.y, p);
                p = fmaf(whA1[G].z, hb.z, p);
                p = fmaf(whA1[G].w, hb.w, p);
                vA[G * 8 + bb] = p;
                float q = wxB[G].x * x.x;
                q = fmaf(wxB[G].y, x.y, q);
                q = fmaf(wxB[G].z, x.z, q);
                q = fmaf(wxB[G].w, x.w, q);
                q = fmaf(whB0[G].x, ha.x, q);
                q = fmaf(whB0[G].y, ha.y, q);
                q = fmaf(whB0[G].z, ha.z, q);
                q = fmaf(whB0[G].w, ha.w, q);
                q = fmaf(whB1[G].x, hb.x, q);
                q = fmaf(whB1[G].y, hb.y, q);
                q = fmaf(whB1[G].z, hb.z, q);
                q = fmaf(whB1[G].w, hb.w, q);
                vB[G * 8 + bb] = q;
            }
        }
        reduce32(vA, lane);
        if ((lane & 1) == 0) {
            const int vi = (lane >> 1) & 31;
            sgate[vi >> 3][2 * w][8 + (vi & 7)] = vA[0];
        }
        reduce32(vB, lane);
        if ((lane & 1) == 0) {
            const int vi = (lane >> 1) & 31;
            sgate[vi >> 3][2 * w + 1][8 + (vi & 7)] = vB[0];
        }

        // ---- Phase F: x(t+1) prefetch (latency hides under epilogue)
        float4 xregA, xregB;
        const bool do_stage = (t + 1 < Tg);
        if (do_stage) {
            const int b = tid >> 5, j = tid & 31;
            const int tok = tokens[(size_t)(g * 16 + b) * T + (t + 1)];
            const float4* er = ((const float4*)emb) + (size_t)tok * 64;
            xregA = er[j];
            xregB = er[32 + j];
        }
        __syncthreads();   // sync 2/3: sgate complete before epilogue reads

        // ---- epilogue: gates + elementwise (tid<256)
        if (tid < 256) {
            const float ai = sgate[0][ul2][b2] + bi_i + bh_i;
            const float af = sgate[1][ul2][b2] + bi_f + bh_f;
            const float ag = sgate[2][ul2][b2] + bi_g + bh_g;
            const float ao = sgate[3][ul2][b2] + bi_o + bh_o;

            const float ig = sigm_f(ai);
            const float fg = sigm_f(af);
            const float gv = tanh_f(ag);
            const float og = sigm_f(ao);

            const float c_old = s_c[tid];
            const float c_new = fg * c_old + ig * gv;
            const float h_new = og * tanh_f(c_new);
            s_c[tid] = c_new;

            const int idx = unit2 * B + bg;
            __hip_atomic_store(&h_buf[(size_t)((t + 1) & 1) * (H * B) + idx],
                               h_new, __ATOMIC_RELAXED,
                               __HIP_MEMORY_SCOPE_AGENT);
            if (t == s_L[b2] - 1) {
                last_h[idx] = h_new;
                last_c[idx] = c_new;
            }
        }
        // x(t+1) LDS write (x-region idle: everyone is past Phase E).
        if (do_stage) {
            const int b = tid >> 5, j = tid & 31;
            float4* dst = (float4*)&xh[b * 772];
            dst[j]      = xregA;
            dst[32 + j] = xregB;

            __syncthreads();   // sync 3/3: drains h sc-stores + x(t+1) visible
            if (tid == 0)
                __hip_atomic_store(&flags[m], t + 1, __ATOMIC_RELAXED,
                                   __HIP_MEMORY_SCOPE_AGENT);
        }
    }
}

// ---------------------------------------------------------------------------
// final: y = [h;c] @ W_proj^T + b_proj ; out = y @ W_out^T + b_out
// grid 128 x 256 (unchanged)
__global__ __launch_bounds__(256) void final_kernel(
    const float* __restrict__ ws_ro, const float* __restrict__ W_proj,
    const float* __restrict__ b_proj, const float* __restrict__ W_out,
    const float* __restrict__ b_out, float* __restrict__ out) {
    const int bg = blockIdx.x, tid = threadIdx.x;
    const float* last_h = ws_ro + LASTH_OFF;
    const float* last_c = ws_ro + LASTC_OFF;

    __shared__ __align__(16) float s_hc[2 * H];
    __shared__ float s_y[H];
    for (int u = tid; u < H; u += 256) {
        s_hc[u]     = last_h[u * B + bg];
        s_hc[H + u] = last_c[u * B + bg];
    }
    __syncthreads();

    const float4* hc4 = (const float4*)s_hc;
    const float4* Wp4 = (const float4*)W_proj;
#pragma unroll
    for (int jj = 0; jj < 2; ++jj) {
        const int j = tid + jj * 256;
        const float4* wr = Wp4 + (size_t)j * 256;
        float4 acc = {0, 0, 0, 0};
#pragma unroll 4
        for (int kq = 0; kq < 256; ++kq) {
            acc.x = fmaf(wr[kq].x, hc4[kq].x, acc.x);
            acc.y = fmaf(wr[kq].y, hc4[kq].y, acc.y);
            acc.z = fmaf(wr[kq].z, hc4[kq].z, acc.z);
            acc.w = fmaf(wr[kq].w, hc4[kq].w, acc.w);
        }
        s_y[j] = acc.x + acc.y + acc.z + acc.w + b_proj[j];
    }
    __syncthreads();

    if (tid < 64) {
        float p0 = 0.f, p1 = 0.f;
        for (int j = tid; j < H; j += 64) {
            const float y = s_y[j];
            p0 = fmaf(y, W_out[j], p0);
            p1 = fmaf(y, W_out[H + j], p1);
        }
#pragma unroll
        for (int off = 32; off; off >>= 1) {
            p0 += __shfl_down(p0, off);
            p1 += __shfl_down(p1, off);
        }
        if (tid == 0) {
            out[bg * 2 + 0] = p0 + b_out[0];
            out[bg * 2 + 1] = p1 + b_out[1];
        }
    }
}

// ---------------------------------------------------------------------------
extern "C" void kernel_launch(void* const* d_in, const int* in_sizes, int n_in,
                              void* d_out, int out_size, void* d_ws, size_t ws_size,
                              hipStream_t stream) {
    const int*   tokens = (const int*)d_in[0];
    const float* emb    = (const float*)d_in[1];
    const float* W_ih   = (const float*)d_in[2];
    const float* b_ih   = (const float*)d_in[3];
    const float* W_hh   = (const float*)d_in[4];
    const float* b_hh   = (const float*)d_in[5];
    const float* W_proj = (const float*)d_in[6];
    const float* b_proj = (const float*)d_in[7];
    const float* W_out  = (const float*)d_in[8];
    const float* b_out  = (const float*)d_in[9];
    const float* h0     = (const float*)d_in[10];
    const float* c0     = (const float*)d_in[11];
    float* out = (float*)d_out;
    float* ws  = (float*)d_ws;

    // zero the per-group flag slots (required every launch/replay)
    hipMemsetAsync((char*)d_ws + (size_t)FLAG_OFF * sizeof(float), 0,
                   8 * 64 * sizeof(int), stream);

    void* kargs[] = {(void*)&tokens, (void*)&emb, (void*)&W_ih, (void*)&b_ih,
                     (void*)&W_hh, (void*)&b_hh, (void*)&h0, (void*)&c0,
                     (void*)&ws};
    // cooperative launch: guarantees all 256 blocks co-resident (1/CU with the
    // volatile LDS pad), which the flag barrier requires.
    hipLaunchCooperativeKernel((const void*)lstm_persistent, dim3(256),
                               dim3(512), kargs, 0, stream);

    hipLaunchKernelGGL(final_kernel, dim3(B), dim3(256), 0, stream,
                       ws, W_proj, b_proj, W_out, b_out, out);
}

// Round 8
// 10528.925 us; speedup vs baseline: 1.0632x; 1.0632x over previous
//
#include <hip/hip_runtime.h>
#include <math.h>

// Problem constants
#define B 128
#define T 1024
#define E 256
#define H 512

// ws layout (floats):
//   h_buf : 2 * [512][128]  (double-buffered, [unit][batch])
//   last_h: [512][128]
//   last_c: [512][128]
//   flags : 8 groups x 64 ints (one 128B slot-line per group; slots 0..31 used)
#define HBUF_OFF   0
#define LASTH_OFF  (2*65536)
#define LASTC_OFF  (3*65536)
#define FLAG_OFF   (4*65536)

// Accurate transcendentals (OCML expf/tanhf).
__device__ __forceinline__ float sigm_f(float x) {
    return 1.f / (1.f + expf(-x));
}
__device__ __forceinline__ float tanh_f(float x) {
    return tanhf(x);
}

// ---- packed f32 math (VOP3P). The compiler does not emit v_pk_*_f32 from
// scalar source; these halve the dot-product issue count (R8's change).
typedef float f32x2 __attribute__((ext_vector_type(2)));
__device__ __forceinline__ f32x2 pk_mul(f32x2 a, f32x2 b) {
    f32x2 d;
    asm("v_pk_mul_f32 %0, %1, %2" : "=v"(d) : "v"(a), "v"(b));
    return d;
}
__device__ __forceinline__ f32x2 pk_fma(f32x2 a, f32x2 b, f32x2 c) {
    f32x2 d;
    asm("v_pk_fma_f32 %0, %1, %2, %3" : "=v"(d) : "v"(a), "v"(b), "v"(c));
    return d;
}
__device__ __forceinline__ f32x2 lo2(float4 a) { return (f32x2){a.x, a.y}; }
__device__ __forceinline__ f32x2 hi2(float4 a) { return (f32x2){a.z, a.w}; }

// 64-lane reduce-scatter of 32 per-lane values: after this, every lane's v[0]
// holds the full 64-lane sum of value index vi=(lane>>1)&31. All indices are
// compile-time (full unroll) -> stays in registers (no scratch).
__device__ __forceinline__ void reduce32(float (&v)[32], int lane) {
#define RR(MASK, HALF)                                                 \
    {                                                                  \
        const bool hi = (lane & MASK) != 0;                            \
        _Pragma("unroll")                                              \
        for (int i = 0; i < HALF; ++i) {                               \
            const float mine   = hi ? v[i + HALF] : v[i];              \
            const float theirs = hi ? v[i] : v[i + HALF];              \
            v[i] = mine + __shfl_xor(theirs, MASK);                    \
        }                                                              \
    }
    RR(32, 16)
    RR(16, 8)
    RR(8, 4)
    RR(4, 2)
    RR(2, 1)
#undef RR
    v[0] = v[0] + __shfl_xor(v[0], 1);
}

// ---------------------------------------------------------------------------
// Persistent LSTM, whole T=1024 loop in one cooperative kernel.
// EXACT R4 structure (the measured best: 8.77 ms): 256 blocks x 1024 threads,
// 16 waves = 16 units (1 unit/wave), __launch_bounds__(1024,4), 64-VGPR
// regime (weights re-fetched from L2 each step, hidden by 4 waves/SIMD),
// 4-__syncthreads per step with flag-store BEFORE the x(t+1) LDS write.
// R5/R6/R7's register-residency attempts all regressed; reverted.
//
// R8 change: dot products use v_pk_fma_f32 / v_pk_mul_f32 (2xf32/instr),
// pairing adjacent K components. 768 -> 512 dot instructions/thread/step.
// (Pairwise summation order differs from the serial fmaf chain -> absmax
// ~1e-7 instead of 0.0; same data, same LDS traffic, same schedule.)
//
// g = bid>>5 (8 batch groups of 16 rows), m = bid&31 (32 unit groups of 16).
// Per-step schedule:
//   A: x-part dots batches 0..7 (no h dep, hides exchange)
//   B: wait h(t) flags (leader wave polls LLC; LDS s_go release)
//   C: stage h(t) -> LDS; sync
//   D: h-part batches 0..7; reduce32; sgate
//   E: full dots batches 8..15; reduce32; sgate
//   F: x(t+1) prefetch to regs; sync (sgate ready); epilogue (tid<256) +
//      h sc-stores; drain-sync; tid0 flag(t+1); x(t+1) LDS write; sync
// Race-freedom: flag=k means "I finished reading h(k-1) AND my h(k) is at
// the LLC". Writers of h(t+2) run only after seeing all flags>=t+1 ->
// buffer (t&1) safe to overwrite. Protocol unchanged since R4 (proven).
__global__ __launch_bounds__(1024, 4) void lstm_persistent(
    const int* __restrict__ tokens, const float* __restrict__ emb,
    const float* __restrict__ W_ih, const float* __restrict__ b_ih,
    const float* __restrict__ W_hh, const float* __restrict__ b_hh,
    const float* __restrict__ h0, const float* __restrict__ c0,
    float* __restrict__ ws) {
    const int tid = threadIdx.x, bid = blockIdx.x;
    const int g = bid >> 5, m = bid & 31;

    float* h_buf  = ws + HBUF_OFF;
    float* last_h = ws + LASTH_OFF;
    float* last_c = ws + LASTC_OFF;
    int*   flags  = (int*)(ws + FLAG_OFF) + g * 64;   // 32 slots in one line

    __shared__ __align__(16) float xh[16 * 772];   // [b][k], row stride 772
    __shared__ float sgate[4][16][17];             // [gate][unit-local][batch]
    __shared__ int   s_L[16];                      // per-batch Lsteps
    __shared__ float s_c[256];                     // c[ul*16+b], block-owned
    __shared__ int   s_go;                         // intra-block release flag
    __shared__ float lds_pad[8192];                // 32KB pad -> LDS>80KB -> 1 block/CU

    // volatile touch: not removable by DCE (keeps the occupancy limiter)
    {
        volatile float* vp = lds_pad;
        for (int i = tid; i < 8192; i += 1024) vp[i] = 0.f;
    }
    if (tid == 0) s_go = 0;

    // ---- per-batch lengths (all 32 blocks of a group compute identical s_L/Tg)
    if (tid < 16) s_L[tid] = T;
    __syncthreads();
    {
        const int b = tid >> 6;
        const int* tb = tokens + (size_t)(g * 16 + b) * T;
        int fz = T;
        for (int p = (tid & 63); p < T; p += 64)
            if (tb[p] == 0) fz = min(fz, p);
        atomicMin(&s_L[b], fz);
    }
    __syncthreads();
    if (tid < 16) {
        const int f = s_L[tid];
        s_L[tid] = (f == 0 || f == T) ? T : f;
    }
    __syncthreads();
    int Tg = 0;
#pragma unroll
    for (int i = 0; i < 16; ++i) Tg = max(Tg, s_L[i]);

    // ---- init block-owned c tile
    if (tid < 256) {
        const int uli = tid >> 4, bi = tid & 15;
        s_c[tid] = c0[(size_t)(g * 16 + bi) * H + (m * 16 + uli)];
    }

    // ---- stage x(0)
    {
        const int b = tid >> 6, kq4 = tid & 63;
        const int tok = tokens[(size_t)(g * 16 + b) * T + 0];
        ((float4*)&xh[b * 772])[kq4] =
            ((const float4*)emb)[(size_t)tok * 64 + kq4];
    }

    // ---- wave/lane roles + weight rows (compiler re-fetches per step from
    //      L2 in the 64-VGPR regime; that is the R4 behavior we keep)
    const int lane = tid & 63;
    const int w    = tid >> 6;            // wave index = local unit
    const int unit = m * 16 + w;
    const float4* Wi4 = (const float4*)W_ih;
    const float4* Wh4 = (const float4*)W_hh;
    float4 wx[4], wh0[4], wh1[4];         // 12 f4
#pragma unroll
    for (int G = 0; G < 4; ++G) {
        wx[G]  = Wi4[((size_t)G * H + unit) * 64 + lane];
        wh0[G] = Wh4[((size_t)G * H + unit) * 128 + lane];
        wh1[G] = Wh4[((size_t)G * H + unit) * 128 + 64 + lane];
    }

    // ---- epilogue constants (used for tid<256; loads in-bounds for all)
    const int ul2 = tid >> 4, b2 = tid & 15;
    const int unit2 = m * 16 + (ul2 & 15);
    const int bg = g * 16 + b2;
    const float bi_i = b_ih[unit2],         bh_i = b_hh[unit2];
    const float bi_f = b_ih[H + unit2],     bh_f = b_hh[H + unit2];
    const float bi_g = b_ih[2 * H + unit2], bh_g = b_hh[2 * H + unit2];
    const float bi_o = b_ih[3 * H + unit2], bh_o = b_hh[3 * H + unit2];

    __syncthreads();   // x(0), s_L, s_c, s_go visible

    float v[32];

    for (int t = 0; t < Tg; ++t) {
        // ---- Phase A: x-part, batches 0..7 (no h dependency; hides exchange)
#pragma unroll
        for (int bb = 0; bb < 8; ++bb) {
            const float4 x = ((const float4*)&xh[bb * 772])[lane];
            const f32x2 x01 = lo2(x), x23 = hi2(x);
#pragma unroll
            for (int G = 0; G < 4; ++G) {
                f32x2 tacc = pk_mul(lo2(wx[G]), x01);
                tacc = pk_fma(hi2(wx[G]), x23, tacc);
                v[G * 8 + bb] = tacc.x + tacc.y;
            }
        }

        // ---- Phase B: wait for h(t) (leader wave polls LLC; LDS release)
        if (t > 0) {
            if (tid < 64) {
                const int* slot = &flags[tid & 31];
                while (true) {
                    const int fv = __hip_atomic_load(slot, __ATOMIC_RELAXED,
                                                     __HIP_MEMORY_SCOPE_AGENT);
                    if (__all(fv >= t)) break;
                    __builtin_amdgcn_s_sleep(1);
                }
                if (tid == 0)
                    __hip_atomic_store(&s_go, t, __ATOMIC_RELAXED,
                                       __HIP_MEMORY_SCOPE_WORKGROUP);
            } else {
                while (__hip_atomic_load(&s_go, __ATOMIC_RELAXED,
                                         __HIP_MEMORY_SCOPE_WORKGROUP) < t)
                    __builtin_amdgcn_s_sleep(1);
            }
        }

        // ---- Phase C: stage h(t) into xh[b][256+u]
        if (t == 0) {
            const int b = tid >> 6, l = tid & 63;
            const float4* h04 = (const float4*)(h0 + (size_t)(g * 16 + b) * H);
            float4* dst = (float4*)&xh[b * 772 + 256];
            dst[l]      = h04[l];
            dst[64 + l] = h04[64 + l];
        } else {
            // coherent 8B loads from LLC (bypass L1/L2; no cache maintenance)
            const unsigned long long* hs8 = (const unsigned long long*)
                (h_buf + (size_t)(t & 1) * (H * B));
            float2 hv[4];
#pragma unroll
            for (int j = 0; j < 4; ++j) {
                const int idx = j * 1024 + tid;        // [0,4096)
                const int u = idx >> 3, bp = idx & 7;
                unsigned long long val = __hip_atomic_load(
                    &hs8[(size_t)u * 64 + g * 8 + bp],
                    __ATOMIC_RELAXED, __HIP_MEMORY_SCOPE_AGENT);
                hv[j] = __builtin_bit_cast(float2, val);
            }
#pragma unroll
            for (int j = 0; j < 4; ++j) {
                const int idx = j * 1024 + tid;
                const int u = idx >> 3, bp = idx & 7;
                xh[(2 * bp) * 772 + 256 + u]     = hv[j].x;
                xh[(2 * bp + 1) * 772 + 256 + u] = hv[j].y;
            }
        }
        __syncthreads();   // sync 1/4

        // ---- Phase D: h-part batches 0..7; reduce; sgate
#pragma unroll
        for (int bb = 0; bb < 8; ++bb) {
            const float4 ha = ((const float4*)&xh[bb * 772])[64 + lane];
            const float4 hb = ((const float4*)&xh[bb * 772])[128 + lane];
            const f32x2 ha01 = lo2(ha), ha23 = hi2(ha);
            const f32x2 hb01 = lo2(hb), hb23 = hi2(hb);
#pragma unroll
            for (int G = 0; G < 4; ++G) {
                f32x2 tacc = pk_mul(lo2(wh0[G]), ha01);
                tacc = pk_fma(hi2(wh0[G]), ha23, tacc);
                tacc = pk_fma(lo2(wh1[G]), hb01, tacc);
                tacc = pk_fma(hi2(wh1[G]), hb23, tacc);
                v[G * 8 + bb] = v[G * 8 + bb] + (tacc.x + tacc.y);
            }
        }
        reduce32(v, lane);
        if ((lane & 1) == 0) {
            const int vi = (lane >> 1) & 31;
            sgate[vi >> 3][w][vi & 7] = v[0];
        }

        // ---- Phase E: full dots batches 8..15; reduce; sgate
#pragma unroll
        for (int bb = 0; bb < 8; ++bb) {
            const float4 x  = ((const float4*)&xh[(8 + bb) * 772])[lane];
            const float4 ha = ((const float4*)&xh[(8 + bb) * 772])[64 + lane];
            const float4 hb = ((const float4*)&xh[(8 + bb) * 772])[128 + lane];
            const f32x2 x01 = lo2(x), x23 = hi2(x);
            const f32x2 ha01 = lo2(ha), ha23 = hi2(ha);
            const f32x2 hb01 = lo2(hb), hb23 = hi2(hb);
#pragma unroll
            for (int G = 0; G < 4; ++G) {
                f32x2 tacc = pk_mul(lo2(wx[G]), x01);
                tacc = pk_fma(hi2(wx[G]), x23, tacc);
                tacc = pk_fma(lo2(wh0[G]), ha01, tacc);
                tacc = pk_fma(hi2(wh0[G]), ha23, tacc);
                tacc = pk_fma(lo2(wh1[G]), hb01, tacc);
                tacc = pk_fma(hi2(wh1[G]), hb23, tacc);
                v[G * 8 + bb] = tacc.x + tacc.y;
            }
        }
        reduce32(v, lane);
        if ((lane & 1) == 0) {
            const int vi = (lane >> 1) & 31;
            sgate[vi >> 3][w][8 + (vi & 7)] = v[0];
        }

        // ---- Phase F: x(t+1) prefetch (latency hides under epilogue)
        float4 xreg;
        const bool do_stage = (t + 1 < Tg);
        if (do_stage) {
            const int b = tid >> 6, kq4 = tid & 63;
            const int tok = tokens[(size_t)(g * 16 + b) * T + (t + 1)];
            xreg = ((const float4*)emb)[(size_t)tok * 64 + kq4];
        }
        __syncthreads();   // sync 2/4: sgate complete before epilogue reads

        // ---- epilogue: gates + elementwise (tid<256)
        if (tid < 256) {
            const float ai = sgate[0][ul2][b2] + bi_i + bh_i;
            const float af = sgate[1][ul2][b2] + bi_f + bh_f;
            const float ag = sgate[2][ul2][b2] + bi_g + bh_g;
            const float ao = sgate[3][ul2][b2] + bi_o + bh_o;

            const float ig = sigm_f(ai);
            const float fg = sigm_f(af);
            const float gv = tanh_f(ag);
            const float og = sigm_f(ao);

            const float c_old = s_c[tid];
            const float c_new = fg * c_old + ig * gv;
            const float h_new = og * tanh_f(c_new);
            s_c[tid] = c_new;

            const int idx = unit2 * B + bg;
            __hip_atomic_store(&h_buf[(size_t)((t + 1) & 1) * (H * B) + idx],
                               h_new, __ATOMIC_RELAXED,
                               __HIP_MEMORY_SCOPE_AGENT);
            if (t == s_L[b2] - 1) {
                last_h[idx] = h_new;
                last_c[idx] = c_new;
            }
        }

        // ---- handoff to step t+1 (R4 ordering: flag right after drain-sync)
        if (do_stage) {
            __syncthreads();   // sync 3/4: drains vmcnt -> h stores at LLC
            if (tid == 0)
                __hip_atomic_store(&flags[m], t + 1, __ATOMIC_RELAXED,
                                   __HIP_MEMORY_SCOPE_AGENT);
            {
                const int b = tid >> 6, kq4 = tid & 63;
                ((float4*)&xh[b * 772])[kq4] = xreg;
            }
            __syncthreads();   // sync 4/4: x(t+1) staged before next Phase A
        }
    }
}

// ---------------------------------------------------------------------------
// final: y = [h;c] @ W_proj^T + b_proj ; out = y @ W_out^T + b_out
// grid 128 x 256 (unchanged)
__global__ __launch_bounds__(256) void final_kernel(
    const float* __restrict__ ws_ro, const float* __restrict__ W_proj,
    const float* __restrict__ b_proj, const float* __restrict__ W_out,
    const float* __restrict__ b_out, float* __restrict__ out) {
    const int bg = blockIdx.x, tid = threadIdx.x;
    const float* last_h = ws_ro + LASTH_OFF;
    const float* last_c = ws_ro + LASTC_OFF;

    __shared__ __align__(16) float s_hc[2 * H];
    __shared__ float s_y[H];
    for (int u = tid; u < H; u += 256) {
        s_hc[u]     = last_h[u * B + bg];
        s_hc[H + u] = last_c[u * B + bg];
    }
    __syncthreads();

    const float4* hc4 = (const float4*)s_hc;
    const float4* Wp4 = (const float4*)W_proj;
#pragma unroll
    for (int jj = 0; jj < 2; ++jj) {
        const int j = tid + jj * 256;
        const float4* wr = Wp4 + (size_t)j * 256;
        float4 acc = {0, 0, 0, 0};
#pragma unroll 4
        for (int kq = 0; kq < 256; ++kq) {
            acc.x = fmaf(wr[kq].x, hc4[kq].x, acc.x);
            acc.y = fmaf(wr[kq].y, hc4[kq].y, acc.y);
            acc.z = fmaf(wr[kq].z, hc4[kq].z, acc.z);
            acc.w = fmaf(wr[kq].w, hc4[kq].w, acc.w);
        }
        s_y[j] = acc.x + acc.y + acc.z + acc.w + b_proj[j];
    }
    __syncthreads();

    if (tid < 64) {
        float p0 = 0.f, p1 = 0.f;
        for (int j = tid; j < H; j += 64) {
            const float y = s_y[j];
            p0 = fmaf(y, W_out[j], p0);
            p1 = fmaf(y, W_out[H + j], p1);
        }
#pragma unroll
        for (int off = 32; off; off >>= 1) {
            p0 += __shfl_down(p0, off);
            p1 += __shfl_down(p1, off);
        }
        if (tid == 0) {
            out[bg * 2 + 0] = p0 + b_out[0];
            out[bg * 2 + 1] = p1 + b_out[1];
        }
    }
}

// ---------------------------------------------------------------------------
extern "C" void kernel_launch(void* const* d_in, const int* in_sizes, int n_in,
                              void* d_out, int out_size, void* d_ws, size_t ws_size,
                              hipStream_t stream) {
    const int*   tokens = (const int*)d_in[0];
    const float* emb    = (const float*)d_in[1];
    const float* W_ih   = (const float*)d_in[2];
    const float* b_ih   = (const float*)d_in[3];
    const float* W_hh   = (const float*)d_in[4];
    const float* b_hh   = (const float*)d_in[5];
    const float* W_proj = (const float*)d_in[6];
    const float* b_proj = (const float*)d_in[7];
    const float* W_out  = (const float*)d_in[8];
    const float* b_out  = (const float*)d_in[9];
    const float* h0     = (const float*)d_in[10];
    const float* c0     = (const float*)d_in[11];
    float* out = (float*)d_out;
    float* ws  = (float*)d_ws;

    // zero the per-group flag slots (required every launch/replay)
    hipMemsetAsync((char*)d_ws + (size_t)FLAG_OFF * sizeof(float), 0,
                   8 * 64 * sizeof(int), stream);

    void* kargs[] = {(void*)&tokens, (void*)&emb, (void*)&W_ih, (void*)&b_ih,
                     (void*)&W_hh, (void*)&b_hh, (void*)&h0, (void*)&c0,
                     (void*)&ws};
    // cooperative launch: guarantees all 256 blocks co-resident (1/CU with the
    // volatile LDS pad), which the flag barrier requires.
    hipLaunchCooperativeKernel((const void*)lstm_persistent, dim3(256),
                               dim3(1024), kargs, 0, stream);

    hipLaunchKernelGGL(final_kernel, dim3(B), dim3(256), 0, stream,
                       ws, W_proj, b_proj, W_out, b_out, out);
}